// Round 1
// baseline (603.912 us; speedup 1.0000x reference)
//
#include <hip/hip_runtime.h>
#include <hip/hip_bf16.h>

#define Nn 30000
#define Ee 400000
#define C1n 15000
#define E2n 100000
#define C2n 7500
#define Bb 16

// ---- workspace layout (float/u32 elements) ----
#define OFF_SUM1   0            // N*32
#define OFF_CNT1   960000       // N
#define OFF_XPKEY  990000       // C1*32 (u32)
#define OFF_POSSUM 1470000      // C1*3
#define OFF_CNTC1  1515000      // C1
#define OFF_BPMAX  1530000      // C1 (i32)
#define OFF_SUM2   1545000      // C1*64
#define OFF_CNT2   2505000      // C1
#define OFF_X3KEY  2520000      // C2*64 (u32)
#define OFF_B2MAX  3000000      // C2 (i32)
#define OFF_GSUM   3007500      // B*64
#define OFF_GCNT   3008524      // B
#define OFF_MAXABS 3008540      // 1 (u32), padded to 3008544
#define ZERO_ELEMS 3008544
#define OFF_X1     3008544      // N*32
#define OFF_XP     3968544      // C1*32
#define OFF_POSP   4448544      // C1*3
#define OFF_CART   4493544      // E2*3
#define OFF_H1     4793544      // E*25
#define OFF_H2     14793544     // E2*25
#define OFF_T2     17293544     // C1*1664
#define OFF_X2     42253544     // C1*64
// total = 43213544 elems = ~173 MB

__device__ __forceinline__ unsigned fkey(float f) {
    unsigned u = __float_as_uint(f);
    return (u >> 31) ? ~u : (u | 0x80000000u);
}
__device__ __forceinline__ float funkey(unsigned k) {
    unsigned u = (k >> 31) ? (k ^ 0x80000000u) : ~k;
    return __uint_as_float(u);
}
__device__ __forceinline__ float elu(float a) { return a > 0.f ? a : expm1f(a); }

// ---- conv1: edge MLP hidden layer ----
__global__ void h1_kernel(const float* __restrict__ ea, const float* __restrict__ w1a,
                          const float* __restrict__ b1a, float* __restrict__ h1) {
    int t = blockIdx.x * 256 + threadIdx.x;
    if (t >= Ee * 25) return;
    int e = t / 25, k = t % 25;
    float a = b1a[k];
#pragma unroll
    for (int j = 0; j < 3; ++j) a += ea[e * 3 + j] * w1a[j * 25 + k];
    h1[t] = fmaxf(a, 0.f);
}

// ---- conv1 message: weights in registers, grid-stride over edges ----
__global__ __launch_bounds__(256, 2) void conv1_msg(
    const float* __restrict__ x, const float* __restrict__ h1,
    const int* __restrict__ ei, const float* __restrict__ w1b,
    const float* __restrict__ b1b, float* __restrict__ sum1, float* __restrict__ cnt1) {
    const int o = threadIdx.x & 31;
    float wreg[25][6];
    float breg[6];
#pragma unroll
    for (int k = 0; k < 25; ++k)
#pragma unroll
        for (int i = 0; i < 6; ++i) wreg[k][i] = w1b[k * 192 + i * 32 + o];
#pragma unroll
    for (int i = 0; i < 6; ++i) breg[i] = b1b[i * 32 + o];

    int slot = (blockIdx.x * blockDim.x + threadIdx.x) >> 5;
    int nslots = (gridDim.x * blockDim.x) >> 5;
    for (int e = slot; e < Ee; e += nslots) {
        int src = ei[e], dst = ei[Ee + e];
        float xs[6];
#pragma unroll
        for (int i = 0; i < 6; ++i) xs[i] = x[src * 6 + i];
        float acc = 0.f;
#pragma unroll
        for (int i = 0; i < 6; ++i) acc += xs[i] * breg[i];
#pragma unroll
        for (int k = 0; k < 25; ++k) {
            float hk = h1[e * 25 + k];
            float w = 0.f;
#pragma unroll
            for (int i = 0; i < 6; ++i) w += xs[i] * wreg[k][i];
            acc += hk * w;
        }
        atomicAdd(&sum1[dst * 32 + o], acc);
        if (o == 0) atomicAdd(&cnt1[dst], 1.0f);
    }
}

__global__ void x1_kernel(const float* __restrict__ sum1, const float* __restrict__ cnt1,
                          const float* __restrict__ x, const float* __restrict__ root1,
                          const float* __restrict__ bias1, float* __restrict__ x1) {
    int t = blockIdx.x * 256 + threadIdx.x;
    if (t >= Nn * 32) return;
    int n = t >> 5, o = t & 31;
    float a = sum1[t] / fmaxf(cnt1[n], 1.f) + bias1[o];
#pragma unroll
    for (int i = 0; i < 6; ++i) a += x[n * 6 + i] * root1[i * 32 + o];
    x1[t] = elu(a);
}

__global__ void pool1_kernel(const float* __restrict__ x1, const float* __restrict__ pos,
                             const int* __restrict__ batch, const int* __restrict__ cluster1,
                             unsigned* __restrict__ xpkey, float* __restrict__ possum,
                             float* __restrict__ cntc1, int* __restrict__ bpmax) {
    int t = blockIdx.x * 256 + threadIdx.x;
    if (t >= Nn * 32) return;
    int n = t >> 5, o = t & 31;
    int c = cluster1[n];
    atomicMax(&xpkey[c * 32 + o], fkey(x1[t]));
    if (o == 0) {
#pragma unroll
        for (int j = 0; j < 3; ++j) atomicAdd(&possum[c * 3 + j], pos[n * 3 + j]);
        atomicAdd(&cntc1[c], 1.f);
        atomicMax(&bpmax[c], batch[n]);
    }
}

__global__ void pool1_final(const unsigned* __restrict__ xpkey, const float* __restrict__ possum,
                            const float* __restrict__ cntc1, float* __restrict__ xp,
                            float* __restrict__ posp) {
    int t = blockIdx.x * 256 + threadIdx.x;
    if (t >= C1n * 32) return;
    int c = t >> 5, o = t & 31;
    unsigned k = xpkey[t];
    xp[t] = k ? funkey(k) : 0.f;
    if (o < 3) posp[c * 3 + o] = possum[c * 3 + o] / fmaxf(cntc1[c], 1.f);
}

__global__ void cart_kernel(const float* __restrict__ posp, const int* __restrict__ ei2,
                            float* __restrict__ cart, unsigned* __restrict__ maxabs) {
    int e = blockIdx.x * 256 + threadIdx.x;
    float mx = 0.f;
    if (e < E2n) {
        int s = ei2[e], d = ei2[E2n + e];
#pragma unroll
        for (int j = 0; j < 3; ++j) {
            float cv = posp[s * 3 + j] - posp[d * 3 + j];
            cart[e * 3 + j] = cv;
            mx = fmaxf(mx, fabsf(cv));
        }
    }
    // wave-level max reduction, one atomic per wave
#pragma unroll
    for (int off = 32; off > 0; off >>= 1) mx = fmaxf(mx, __shfl_xor(mx, off));
    if ((threadIdx.x & 63) == 0) atomicMax(maxabs, __float_as_uint(mx));
}

__global__ void h2_kernel(const float* __restrict__ cart, const unsigned* __restrict__ maxabs,
                          const float* __restrict__ w2a, const float* __restrict__ b2a,
                          float* __restrict__ h2) {
    int t = blockIdx.x * 256 + threadIdx.x;
    if (t >= E2n * 25) return;
    int e = t / 25, k = t % 25;
    float inv = 0.5f / __uint_as_float(maxabs[0]);  // 1/(2*max)
    float a = b2a[k];
#pragma unroll
    for (int j = 0; j < 3; ++j) a += (cart[e * 3 + j] * inv + 0.5f) * w2a[j * 25 + k];
    h2[t] = fmaxf(a, 0.f);
}

// ---- T2[n, k, o] = sum_i xp[n,i] * w2baug[k,i,o]; k=25 row = bias ----
__global__ __launch_bounds__(256) void t2_gemm(const float* __restrict__ xp,
                                               const float* __restrict__ w2b,
                                               const float* __restrict__ b2b,
                                               float* __restrict__ T2) {
    __shared__ float As[64][33];
    __shared__ __align__(16) float Bs[32][68];
    int bm = blockIdx.x * 64;
    int bn = blockIdx.y * 64;
    int t = threadIdx.x;
#pragma unroll
    for (int r = 0; r < 8; ++r) {
        int idx = t + r * 256;
        int m = idx >> 5, i = idx & 31;
        int n = bm + m;
        As[m][i] = (n < C1n) ? xp[n * 32 + i] : 0.f;
    }
#pragma unroll
    for (int r = 0; r < 8; ++r) {
        int idx = t + r * 256;
        int i = idx >> 6, nn = idx & 63;
        int col = bn + nn;
        float v;
        if (col < 1600) { int k = col >> 6, o = col & 63; v = w2b[k * 2048 + i * 64 + o]; }
        else            { v = b2b[i * 64 + (col & 63)]; }
        Bs[i][nn] = v;
    }
    __syncthreads();
    int tm4 = (t >> 4) << 2;
    int tn4 = (t & 15) << 2;
    float acc[4][4] = {};
#pragma unroll
    for (int i = 0; i < 32; ++i) {
        float a0 = As[tm4][i], a1 = As[tm4 + 1][i], a2 = As[tm4 + 2][i], a3 = As[tm4 + 3][i];
        float4 bv = *reinterpret_cast<const float4*>(&Bs[i][tn4]);
        acc[0][0] += a0 * bv.x; acc[0][1] += a0 * bv.y; acc[0][2] += a0 * bv.z; acc[0][3] += a0 * bv.w;
        acc[1][0] += a1 * bv.x; acc[1][1] += a1 * bv.y; acc[1][2] += a1 * bv.z; acc[1][3] += a1 * bv.w;
        acc[2][0] += a2 * bv.x; acc[2][1] += a2 * bv.y; acc[2][2] += a2 * bv.z; acc[2][3] += a2 * bv.w;
        acc[3][0] += a3 * bv.x; acc[3][1] += a3 * bv.y; acc[3][2] += a3 * bv.z; acc[3][3] += a3 * bv.w;
    }
#pragma unroll
    for (int r = 0; r < 4; ++r) {
        int row = bm + tm4 + r;
        if (row < C1n) {
            float4 v = make_float4(acc[r][0], acc[r][1], acc[r][2], acc[r][3]);
            *reinterpret_cast<float4*>(&T2[(size_t)row * 1664 + bn + tn4]) = v;
        }
    }
}

__global__ void conv2_msg(const float* __restrict__ T2, const float* __restrict__ h2,
                          const int* __restrict__ ei2, float* __restrict__ sum2,
                          float* __restrict__ cnt2) {
    int t = blockIdx.x * 256 + threadIdx.x;
    if (t >= E2n * 64) return;
    int e = t >> 6, o = t & 63;
    int src = ei2[e], dst = ei2[E2n + e];
    const float* Trow = T2 + (size_t)src * 1664;
    float acc = Trow[25 * 64 + o];  // bias row
#pragma unroll
    for (int k = 0; k < 25; ++k) acc += h2[e * 25 + k] * Trow[k * 64 + o];
    atomicAdd(&sum2[dst * 64 + o], acc);
    if (o == 0) atomicAdd(&cnt2[dst], 1.f);
}

__global__ void x2_kernel(const float* __restrict__ sum2, const float* __restrict__ cnt2,
                          const float* __restrict__ xp, const float* __restrict__ root2,
                          const float* __restrict__ bias2, float* __restrict__ x2) {
    int t = blockIdx.x * 256 + threadIdx.x;
    if (t >= C1n * 64) return;
    int c = t >> 6, o = t & 63;
    float a = sum2[t] / fmaxf(cnt2[c], 1.f) + bias2[o];
#pragma unroll
    for (int i = 0; i < 32; ++i) a += xp[c * 32 + i] * root2[i * 64 + o];
    x2[t] = elu(a);
}

__global__ void pool2_kernel(const float* __restrict__ x2, const int* __restrict__ cluster2,
                             const int* __restrict__ bpmax, unsigned* __restrict__ x3key,
                             int* __restrict__ b2max) {
    int t = blockIdx.x * 256 + threadIdx.x;
    if (t >= C1n * 64) return;
    int c = t >> 6, o = t & 63;
    int c2 = cluster2[c];
    atomicMax(&x3key[c2 * 64 + o], fkey(x2[t]));
    if (o == 0) atomicMax(&b2max[c2], bpmax[c]);
}

__global__ void gacc_kernel(const unsigned* __restrict__ x3key, const int* __restrict__ b2max,
                            float* __restrict__ gsum, float* __restrict__ gcnt) {
    int t = blockIdx.x * 256 + threadIdx.x;
    if (t >= C2n * 64) return;
    int c = t >> 6, o = t & 63;
    int b = b2max[c];
    unsigned k = x3key[t];
    float v = k ? funkey(k) : 0.f;
    atomicAdd(&gsum[b * 64 + o], v);
    if (o == 0) atomicAdd(&gcnt[b], 1.f);
}

__global__ void head_kernel(const float* __restrict__ gsum, const float* __restrict__ gcnt,
                            const float* __restrict__ fc1w, const float* __restrict__ fc1b,
                            const float* __restrict__ fc2w, const float* __restrict__ fc2b,
                            float* __restrict__ out) {
    __shared__ float g[16 * 64];
    __shared__ float hb[16 * 128];
    __shared__ float lg[16 * 10];
    __shared__ float rowm[16];
    int t = threadIdx.x;
    for (int idx = t; idx < 16 * 64; idx += 256) {
        int b = idx >> 6;
        g[idx] = gsum[idx] / fmaxf(gcnt[b], 1.f);
    }
    __syncthreads();
    for (int idx = t; idx < 16 * 128; idx += 256) {
        int b = idx >> 7, j = idx & 127;
        float a = fc1b[j];
        for (int i = 0; i < 64; ++i) a += g[b * 64 + i] * fc1w[i * 128 + j];
        hb[idx] = elu(a);
    }
    __syncthreads();
    for (int idx = t; idx < 160; idx += 256) {
        int b = idx / 10, c = idx % 10;
        float a = fc2b[c];
        for (int i = 0; i < 128; ++i) a += hb[b * 128 + i] * fc2w[i * 10 + c];
        lg[idx] = a;
    }
    __syncthreads();
    if (t < 16) {
        float m = -1e30f;
        for (int c = 0; c < 10; ++c) m = fmaxf(m, lg[t * 10 + c]);
        float s = 0.f;
        for (int c = 0; c < 10; ++c) s += expf(lg[t * 10 + c] - m);
        rowm[t] = m + logf(s);
    }
    __syncthreads();
    for (int idx = t; idx < 160; idx += 256) out[idx] = lg[idx] - rowm[idx / 10];
}

extern "C" void kernel_launch(void* const* d_in, const int* in_sizes, int n_in,
                              void* d_out, int out_size, void* d_ws, size_t ws_size,
                              hipStream_t stream) {
    const float* x     = (const float*)d_in[0];
    const float* ea    = (const float*)d_in[1];
    const float* pos   = (const float*)d_in[2];
    const int*   ei    = (const int*)d_in[3];
    const int*   batch = (const int*)d_in[4];
    const int*   cl1   = (const int*)d_in[5];
    const int*   ei2   = (const int*)d_in[6];
    const int*   cl2   = (const int*)d_in[7];
    const float* w1a   = (const float*)d_in[8];
    const float* b1a   = (const float*)d_in[9];
    const float* w1b   = (const float*)d_in[10];
    const float* b1b   = (const float*)d_in[11];
    const float* root1 = (const float*)d_in[12];
    const float* bias1 = (const float*)d_in[13];
    const float* w2a   = (const float*)d_in[14];
    const float* b2a   = (const float*)d_in[15];
    const float* w2b   = (const float*)d_in[16];
    const float* b2b   = (const float*)d_in[17];
    const float* root2 = (const float*)d_in[18];
    const float* bias2 = (const float*)d_in[19];
    const float* fc1w  = (const float*)d_in[20];
    const float* fc1b  = (const float*)d_in[21];
    const float* fc2w  = (const float*)d_in[22];
    const float* fc2b  = (const float*)d_in[23];
    float* out = (float*)d_out;

    float* ws = (float*)d_ws;
    float*    sum1   = ws + OFF_SUM1;
    float*    cnt1   = ws + OFF_CNT1;
    unsigned* xpkey  = (unsigned*)(ws + OFF_XPKEY);
    float*    possum = ws + OFF_POSSUM;
    float*    cntc1  = ws + OFF_CNTC1;
    int*      bpmax  = (int*)(ws + OFF_BPMAX);
    float*    sum2   = ws + OFF_SUM2;
    float*    cnt2   = ws + OFF_CNT2;
    unsigned* x3key  = (unsigned*)(ws + OFF_X3KEY);
    int*      b2max  = (int*)(ws + OFF_B2MAX);
    float*    gsum   = ws + OFF_GSUM;
    float*    gcnt   = ws + OFF_GCNT;
    unsigned* maxabs = (unsigned*)(ws + OFF_MAXABS);
    float*    x1     = ws + OFF_X1;
    float*    xp     = ws + OFF_XP;
    float*    posp   = ws + OFF_POSP;
    float*    cart   = ws + OFF_CART;
    float*    h1     = ws + OFF_H1;
    float*    h2     = ws + OFF_H2;
    float*    T2     = ws + OFF_T2;
    float*    x2     = ws + OFF_X2;

    hipMemsetAsync(ws, 0, (size_t)ZERO_ELEMS * 4, stream);

    h1_kernel<<<(Ee * 25 + 255) / 256, 256, 0, stream>>>(ea, w1a, b1a, h1);
    conv1_msg<<<1024, 256, 0, stream>>>(x, h1, ei, w1b, b1b, sum1, cnt1);
    x1_kernel<<<(Nn * 32 + 255) / 256, 256, 0, stream>>>(sum1, cnt1, x, root1, bias1, x1);
    pool1_kernel<<<(Nn * 32 + 255) / 256, 256, 0, stream>>>(x1, pos, batch, cl1, xpkey, possum, cntc1, bpmax);
    pool1_final<<<(C1n * 32 + 255) / 256, 256, 0, stream>>>(xpkey, possum, cntc1, xp, posp);
    cart_kernel<<<(E2n + 255) / 256, 256, 0, stream>>>(posp, ei2, cart, maxabs);
    h2_kernel<<<(E2n * 25 + 255) / 256, 256, 0, stream>>>(cart, maxabs, w2a, b2a, h2);
    dim3 tgrid((C1n + 63) / 64, 1664 / 64);
    t2_gemm<<<tgrid, 256, 0, stream>>>(xp, w2b, b2b, T2);
    conv2_msg<<<(E2n * 64 + 255) / 256, 256, 0, stream>>>(T2, h2, ei2, sum2, cnt2);
    x2_kernel<<<(C1n * 64 + 255) / 256, 256, 0, stream>>>(sum2, cnt2, xp, root2, bias2, x2);
    pool2_kernel<<<(C1n * 64 + 255) / 256, 256, 0, stream>>>(x2, cl2, bpmax, x3key, b2max);
    gacc_kernel<<<(C2n * 64 + 255) / 256, 256, 0, stream>>>(x3key, b2max, gsum, gcnt);
    head_kernel<<<1, 256, 0, stream>>>(gsum, gcnt, fc1w, fc1b, fc2w, fc2b, out);
}

// Round 2
// 471.339 us; speedup vs baseline: 1.2813x; 1.2813x over previous
//
#include <hip/hip_runtime.h>
#include <hip/hip_bf16.h>

#define Nn 30000
#define Ee 400000
#define C1n 15000
#define E2n 100000
#define C2n 7500
#define Bb 16

// ---- workspace layout (float/u32 elements) ----
#define OFF_SUM1   0            // N*32
#define OFF_CNT1   960000       // N
#define OFF_XPKEY  990000       // C1*32 (u32)
#define OFF_POSSUM 1470000      // C1*3
#define OFF_CNTC1  1515000      // C1
#define OFF_BPMAX  1530000      // C1 (i32)
#define OFF_SUM2   1545000      // C1*64
#define OFF_CNT2   2505000      // C1
#define OFF_X3KEY  2520000      // C2*64 (u32)
#define OFF_B2MAX  3000000      // C2 (i32)
#define OFF_GSUM   3007500      // B*64
#define OFF_GCNT   3008524      // B
#define OFF_MAXABS 3008540      // 1 (u32), padded to 3008544
#define ZERO_ELEMS 3008544
#define OFF_X1     3008544      // N*32
#define OFF_XP     3968544      // C1*32
#define OFF_POSP   4448544      // C1*3
#define OFF_CART   4493544      // E2*3
#define OFF_H1     4793544      // E*25
#define OFF_H2     14793544     // E2*25
#define OFF_T2     17293544     // C1*1664 bf16 (ushort) = 12,480,000 float slots
#define OFF_X2     29773544     // C1*64
// total = 30,733,544 elems = ~123 MB

__device__ __forceinline__ unsigned fkey(float f) {
    unsigned u = __float_as_uint(f);
    return (u >> 31) ? ~u : (u | 0x80000000u);
}
__device__ __forceinline__ float funkey(unsigned k) {
    unsigned u = (k >> 31) ? (k ^ 0x80000000u) : ~k;
    return __uint_as_float(u);
}
__device__ __forceinline__ float elu(float a) { return a > 0.f ? a : expm1f(a); }

__device__ __forceinline__ unsigned short f2bf(float f) {
    unsigned u = __float_as_uint(f);
    unsigned lsb = (u >> 16) & 1u;
    u += 0x7fffu + lsb;  // round to nearest even
    return (unsigned short)(u >> 16);
}
__device__ __forceinline__ float bf2f(unsigned short s) {
    return __uint_as_float(((unsigned)s) << 16);
}

// ---- conv1: edge MLP hidden layer ----
__global__ void h1_kernel(const float* __restrict__ ea, const float* __restrict__ w1a,
                          const float* __restrict__ b1a, float* __restrict__ h1) {
    int t = blockIdx.x * 256 + threadIdx.x;
    if (t >= Ee * 25) return;
    int e = t / 25, k = t % 25;
    float a = b1a[k];
#pragma unroll
    for (int j = 0; j < 3; ++j) a += ea[e * 3 + j] * w1a[j * 25 + k];
    h1[t] = fmaxf(a, 0.f);
}

// ---- conv1 message: weights in registers, grid-stride over edges ----
__global__ __launch_bounds__(256, 2) void conv1_msg(
    const float* __restrict__ x, const float* __restrict__ h1,
    const int* __restrict__ ei, const float* __restrict__ w1b,
    const float* __restrict__ b1b, float* __restrict__ sum1, float* __restrict__ cnt1) {
    const int o = threadIdx.x & 31;
    float wreg[25][6];
    float breg[6];
#pragma unroll
    for (int k = 0; k < 25; ++k)
#pragma unroll
        for (int i = 0; i < 6; ++i) wreg[k][i] = w1b[k * 192 + i * 32 + o];
#pragma unroll
    for (int i = 0; i < 6; ++i) breg[i] = b1b[i * 32 + o];

    int slot = (blockIdx.x * blockDim.x + threadIdx.x) >> 5;
    int nslots = (gridDim.x * blockDim.x) >> 5;
    for (int e = slot; e < Ee; e += nslots) {
        int src = ei[e], dst = ei[Ee + e];
        float xs[6];
#pragma unroll
        for (int i = 0; i < 6; ++i) xs[i] = x[src * 6 + i];
        float acc = 0.f;
#pragma unroll
        for (int i = 0; i < 6; ++i) acc += xs[i] * breg[i];
#pragma unroll
        for (int k = 0; k < 25; ++k) {
            float hk = h1[e * 25 + k];
            float w = 0.f;
#pragma unroll
            for (int i = 0; i < 6; ++i) w += xs[i] * wreg[k][i];
            acc += hk * w;
        }
        atomicAdd(&sum1[dst * 32 + o], acc);
        if (o == 0) atomicAdd(&cnt1[dst], 1.0f);
    }
}

__global__ void x1_kernel(const float* __restrict__ sum1, const float* __restrict__ cnt1,
                          const float* __restrict__ x, const float* __restrict__ root1,
                          const float* __restrict__ bias1, float* __restrict__ x1) {
    int t = blockIdx.x * 256 + threadIdx.x;
    if (t >= Nn * 32) return;
    int n = t >> 5, o = t & 31;
    float a = sum1[t] / fmaxf(cnt1[n], 1.f) + bias1[o];
#pragma unroll
    for (int i = 0; i < 6; ++i) a += x[n * 6 + i] * root1[i * 32 + o];
    x1[t] = elu(a);
}

__global__ void pool1_kernel(const float* __restrict__ x1, const float* __restrict__ pos,
                             const int* __restrict__ batch, const int* __restrict__ cluster1,
                             unsigned* __restrict__ xpkey, float* __restrict__ possum,
                             float* __restrict__ cntc1, int* __restrict__ bpmax) {
    int t = blockIdx.x * 256 + threadIdx.x;
    if (t >= Nn * 32) return;
    int n = t >> 5, o = t & 31;
    int c = cluster1[n];
    atomicMax(&xpkey[c * 32 + o], fkey(x1[t]));
    if (o == 0) {
#pragma unroll
        for (int j = 0; j < 3; ++j) atomicAdd(&possum[c * 3 + j], pos[n * 3 + j]);
        atomicAdd(&cntc1[c], 1.f);
        atomicMax(&bpmax[c], batch[n]);
    }
}

__global__ void pool1_final(const unsigned* __restrict__ xpkey, const float* __restrict__ possum,
                            const float* __restrict__ cntc1, float* __restrict__ xp,
                            float* __restrict__ posp) {
    int t = blockIdx.x * 256 + threadIdx.x;
    if (t >= C1n * 32) return;
    int c = t >> 5, o = t & 31;
    unsigned k = xpkey[t];
    xp[t] = k ? funkey(k) : 0.f;
    if (o < 3) posp[c * 3 + o] = possum[c * 3 + o] / fmaxf(cntc1[c], 1.f);
}

__global__ void cart_kernel(const float* __restrict__ posp, const int* __restrict__ ei2,
                            float* __restrict__ cart, unsigned* __restrict__ maxabs) {
    int e = blockIdx.x * 256 + threadIdx.x;
    float mx = 0.f;
    if (e < E2n) {
        int s = ei2[e], d = ei2[E2n + e];
#pragma unroll
        for (int j = 0; j < 3; ++j) {
            float cv = posp[s * 3 + j] - posp[d * 3 + j];
            cart[e * 3 + j] = cv;
            mx = fmaxf(mx, fabsf(cv));
        }
    }
#pragma unroll
    for (int off = 32; off > 0; off >>= 1) mx = fmaxf(mx, __shfl_xor(mx, off));
    if ((threadIdx.x & 63) == 0) atomicMax(maxabs, __float_as_uint(mx));
}

__global__ void h2_kernel(const float* __restrict__ cart, const unsigned* __restrict__ maxabs,
                          const float* __restrict__ w2a, const float* __restrict__ b2a,
                          float* __restrict__ h2) {
    int t = blockIdx.x * 256 + threadIdx.x;
    if (t >= E2n * 25) return;
    int e = t / 25, k = t % 25;
    float inv = 0.5f / __uint_as_float(maxabs[0]);  // 1/(2*max)
    float a = b2a[k];
#pragma unroll
    for (int j = 0; j < 3; ++j) a += (cart[e * 3 + j] * inv + 0.5f) * w2a[j * 25 + k];
    h2[t] = fmaxf(a, 0.f);
}

// ---- T2[n, k, o] = sum_i xp[n,i] * w2baug[k,i,o]; k=25 row = bias; bf16 out ----
// 256 rows x 64 cols per block. B-tile loaded once; A staged in LDS (pad +4).
// Each thread: 4 cols (tn4), 2 rows per k-sweep (Bs read amortized over 8 FMA).
__global__ __launch_bounds__(256) void t2_gemm(const float* __restrict__ xp,
                                               const float* __restrict__ w2b,
                                               const float* __restrict__ b2b,
                                               unsigned short* __restrict__ T2) {
    __shared__ float As[256 * 36];          // 256 rows, stride 36 (pad kills bank alias)
    __shared__ float Bs[32][68];
    const int bm = blockIdx.x * 256;
    const int bn = blockIdx.y * 64;
    const int t = threadIdx.x;
#pragma unroll
    for (int r = 0; r < 8; ++r) {
        int q = t + r * 256;               // quad index over 256x32
        int row = q >> 3, i4 = (q & 7) * 4;
        int n = bm + row;
        float4 v = make_float4(0.f, 0.f, 0.f, 0.f);
        if (n < C1n) v = *reinterpret_cast<const float4*>(&xp[n * 32 + i4]);
        *reinterpret_cast<float4*>(&As[row * 36 + i4]) = v;
    }
#pragma unroll
    for (int r = 0; r < 8; ++r) {
        int idx = t + r * 256;
        int i = idx >> 6, nn = idx & 63;
        int col = bn + nn;
        float v;
        if (col < 1600) { int k = col >> 6, o = col & 63; v = w2b[k * 2048 + i * 64 + o]; }
        else            { v = b2b[i * 64 + (col & 63)]; }
        Bs[i][nn] = v;
    }
    __syncthreads();
    const int tn4 = (t & 15) * 4;
    const int tr = t >> 4;                  // 0..15
    for (int it = 0; it < 8; ++it) {
        int r0 = it * 32 + tr, r1 = r0 + 16;
        float a0[32], a1[32];
#pragma unroll
        for (int q = 0; q < 8; ++q) {
            *reinterpret_cast<float4*>(&a0[q * 4]) = *reinterpret_cast<const float4*>(&As[r0 * 36 + q * 4]);
            *reinterpret_cast<float4*>(&a1[q * 4]) = *reinterpret_cast<const float4*>(&As[r1 * 36 + q * 4]);
        }
        float acc0[4] = {0.f, 0.f, 0.f, 0.f}, acc1[4] = {0.f, 0.f, 0.f, 0.f};
#pragma unroll
        for (int k = 0; k < 32; ++k) {
            float4 bv = *reinterpret_cast<const float4*>(&Bs[k][tn4]);
            acc0[0] += a0[k] * bv.x; acc0[1] += a0[k] * bv.y;
            acc0[2] += a0[k] * bv.z; acc0[3] += a0[k] * bv.w;
            acc1[0] += a1[k] * bv.x; acc1[1] += a1[k] * bv.y;
            acc1[2] += a1[k] * bv.z; acc1[3] += a1[k] * bv.w;
        }
        int row0 = bm + r0, row1 = bm + r1;
        if (row0 < C1n) {
            union { unsigned short us[4]; uint2 v; } pk;
            pk.us[0] = f2bf(acc0[0]); pk.us[1] = f2bf(acc0[1]);
            pk.us[2] = f2bf(acc0[2]); pk.us[3] = f2bf(acc0[3]);
            *reinterpret_cast<uint2*>(&T2[(size_t)row0 * 1664 + bn + tn4]) = pk.v;
        }
        if (row1 < C1n) {
            union { unsigned short us[4]; uint2 v; } pk;
            pk.us[0] = f2bf(acc1[0]); pk.us[1] = f2bf(acc1[1]);
            pk.us[2] = f2bf(acc1[2]); pk.us[3] = f2bf(acc1[3]);
            *reinterpret_cast<uint2*>(&T2[(size_t)row1 * 1664 + bn + tn4]) = pk.v;
        }
    }
}

__global__ void conv2_msg(const unsigned short* __restrict__ T2, const float* __restrict__ h2,
                          const int* __restrict__ ei2, float* __restrict__ sum2,
                          float* __restrict__ cnt2) {
    int t = blockIdx.x * 256 + threadIdx.x;
    if (t >= E2n * 64) return;
    int e = t >> 6, o = t & 63;
    int src = ei2[e], dst = ei2[E2n + e];
    const unsigned short* Trow = T2 + (size_t)src * 1664;
    float acc = bf2f(Trow[25 * 64 + o]);  // bias row
#pragma unroll
    for (int k = 0; k < 25; ++k) acc += h2[e * 25 + k] * bf2f(Trow[k * 64 + o]);
    atomicAdd(&sum2[dst * 64 + o], acc);
    if (o == 0) atomicAdd(&cnt2[dst], 1.f);
}

__global__ void x2_kernel(const float* __restrict__ sum2, const float* __restrict__ cnt2,
                          const float* __restrict__ xp, const float* __restrict__ root2,
                          const float* __restrict__ bias2, float* __restrict__ x2) {
    int t = blockIdx.x * 256 + threadIdx.x;
    if (t >= C1n * 64) return;
    int c = t >> 6, o = t & 63;
    float a = sum2[t] / fmaxf(cnt2[c], 1.f) + bias2[o];
#pragma unroll
    for (int i = 0; i < 32; ++i) a += xp[c * 32 + i] * root2[i * 64 + o];
    x2[t] = elu(a);
}

__global__ void pool2_kernel(const float* __restrict__ x2, const int* __restrict__ cluster2,
                             const int* __restrict__ bpmax, unsigned* __restrict__ x3key,
                             int* __restrict__ b2max) {
    int t = blockIdx.x * 256 + threadIdx.x;
    if (t >= C1n * 64) return;
    int c = t >> 6, o = t & 63;
    int c2 = cluster2[c];
    atomicMax(&x3key[c2 * 64 + o], fkey(x2[t]));
    if (o == 0) atomicMax(&b2max[c2], bpmax[c]);
}

__global__ void gacc_kernel(const unsigned* __restrict__ x3key, const int* __restrict__ b2max,
                            float* __restrict__ gsum, float* __restrict__ gcnt) {
    int t = blockIdx.x * 256 + threadIdx.x;
    if (t >= C2n * 64) return;
    int c = t >> 6, o = t & 63;
    int b = b2max[c];
    unsigned k = x3key[t];
    float v = k ? funkey(k) : 0.f;
    atomicAdd(&gsum[b * 64 + o], v);
    if (o == 0) atomicAdd(&gcnt[b], 1.f);
}

__global__ void head_kernel(const float* __restrict__ gsum, const float* __restrict__ gcnt,
                            const float* __restrict__ fc1w, const float* __restrict__ fc1b,
                            const float* __restrict__ fc2w, const float* __restrict__ fc2b,
                            float* __restrict__ out) {
    __shared__ float g[16 * 64];
    __shared__ float hb[16 * 128];
    __shared__ float lg[16 * 10];
    __shared__ float rowm[16];
    int t = threadIdx.x;
    for (int idx = t; idx < 16 * 64; idx += 256) {
        int b = idx >> 6;
        g[idx] = gsum[idx] / fmaxf(gcnt[b], 1.f);
    }
    __syncthreads();
    for (int idx = t; idx < 16 * 128; idx += 256) {
        int b = idx >> 7, j = idx & 127;
        float a = fc1b[j];
        for (int i = 0; i < 64; ++i) a += g[b * 64 + i] * fc1w[i * 128 + j];
        hb[idx] = elu(a);
    }
    __syncthreads();
    for (int idx = t; idx < 160; idx += 256) {
        int b = idx / 10, c = idx % 10;
        float a = fc2b[c];
        for (int i = 0; i < 128; ++i) a += hb[b * 128 + i] * fc2w[i * 10 + c];
        lg[idx] = a;
    }
    __syncthreads();
    if (t < 16) {
        float m = -1e30f;
        for (int c = 0; c < 10; ++c) m = fmaxf(m, lg[t * 10 + c]);
        float s = 0.f;
        for (int c = 0; c < 10; ++c) s += expf(lg[t * 10 + c] - m);
        rowm[t] = m + logf(s);
    }
    __syncthreads();
    for (int idx = t; idx < 160; idx += 256) out[idx] = lg[idx] - rowm[idx / 10];
}

extern "C" void kernel_launch(void* const* d_in, const int* in_sizes, int n_in,
                              void* d_out, int out_size, void* d_ws, size_t ws_size,
                              hipStream_t stream) {
    const float* x     = (const float*)d_in[0];
    const float* ea    = (const float*)d_in[1];
    const float* pos   = (const float*)d_in[2];
    const int*   ei    = (const int*)d_in[3];
    const int*   batch = (const int*)d_in[4];
    const int*   cl1   = (const int*)d_in[5];
    const int*   ei2   = (const int*)d_in[6];
    const int*   cl2   = (const int*)d_in[7];
    const float* w1a   = (const float*)d_in[8];
    const float* b1a   = (const float*)d_in[9];
    const float* w1b   = (const float*)d_in[10];
    const float* b1b   = (const float*)d_in[11];
    const float* root1 = (const float*)d_in[12];
    const float* bias1 = (const float*)d_in[13];
    const float* w2a   = (const float*)d_in[14];
    const float* b2a   = (const float*)d_in[15];
    const float* w2b   = (const float*)d_in[16];
    const float* b2b   = (const float*)d_in[17];
    const float* root2 = (const float*)d_in[18];
    const float* bias2 = (const float*)d_in[19];
    const float* fc1w  = (const float*)d_in[20];
    const float* fc1b  = (const float*)d_in[21];
    const float* fc2w  = (const float*)d_in[22];
    const float* fc2b  = (const float*)d_in[23];
    float* out = (float*)d_out;

    float* ws = (float*)d_ws;
    float*    sum1   = ws + OFF_SUM1;
    float*    cnt1   = ws + OFF_CNT1;
    unsigned* xpkey  = (unsigned*)(ws + OFF_XPKEY);
    float*    possum = ws + OFF_POSSUM;
    float*    cntc1  = ws + OFF_CNTC1;
    int*      bpmax  = (int*)(ws + OFF_BPMAX);
    float*    sum2   = ws + OFF_SUM2;
    float*    cnt2   = ws + OFF_CNT2;
    unsigned* x3key  = (unsigned*)(ws + OFF_X3KEY);
    int*      b2max  = (int*)(ws + OFF_B2MAX);
    float*    gsum   = ws + OFF_GSUM;
    float*    gcnt   = ws + OFF_GCNT;
    unsigned* maxabs = (unsigned*)(ws + OFF_MAXABS);
    float*    x1     = ws + OFF_X1;
    float*    xp     = ws + OFF_XP;
    float*    posp   = ws + OFF_POSP;
    float*    cart   = ws + OFF_CART;
    float*    h1     = ws + OFF_H1;
    float*    h2     = ws + OFF_H2;
    unsigned short* T2 = (unsigned short*)(ws + OFF_T2);
    float*    x2     = ws + OFF_X2;

    hipMemsetAsync(ws, 0, (size_t)ZERO_ELEMS * 4, stream);

    h1_kernel<<<(Ee * 25 + 255) / 256, 256, 0, stream>>>(ea, w1a, b1a, h1);
    conv1_msg<<<1024, 256, 0, stream>>>(x, h1, ei, w1b, b1b, sum1, cnt1);
    x1_kernel<<<(Nn * 32 + 255) / 256, 256, 0, stream>>>(sum1, cnt1, x, root1, bias1, x1);
    pool1_kernel<<<(Nn * 32 + 255) / 256, 256, 0, stream>>>(x1, pos, batch, cl1, xpkey, possum, cntc1, bpmax);
    pool1_final<<<(C1n * 32 + 255) / 256, 256, 0, stream>>>(xpkey, possum, cntc1, xp, posp);
    cart_kernel<<<(E2n + 255) / 256, 256, 0, stream>>>(posp, ei2, cart, maxabs);
    h2_kernel<<<(E2n * 25 + 255) / 256, 256, 0, stream>>>(cart, maxabs, w2a, b2a, h2);
    dim3 tgrid((C1n + 255) / 256, 26);
    t2_gemm<<<tgrid, 256, 0, stream>>>(xp, w2b, b2b, T2);
    conv2_msg<<<(E2n * 64 + 255) / 256, 256, 0, stream>>>(T2, h2, ei2, sum2, cnt2);
    x2_kernel<<<(C1n * 64 + 255) / 256, 256, 0, stream>>>(sum2, cnt2, xp, root2, bias2, x2);
    pool2_kernel<<<(C1n * 64 + 255) / 256, 256, 0, stream>>>(x2, cl2, bpmax, x3key, b2max);
    gacc_kernel<<<(C2n * 64 + 255) / 256, 256, 0, stream>>>(x3key, b2max, gsum, gcnt);
    head_kernel<<<1, 256, 0, stream>>>(gsum, gcnt, fc1w, fc1b, fc2w, fc2b, out);
}

// Round 3
// 408.517 us; speedup vs baseline: 1.4783x; 1.1538x over previous
//
#include <hip/hip_runtime.h>
#include <hip/hip_bf16.h>

#define Nn 30000
#define Ee 400000
#define C1n 15000
#define E2n 100000
#define C2n 7500
#define Bb 16

// ---- workspace layout (float/u32 elements) ----
#define OFF_SUM1   0            // N*32
#define OFF_CNT1   960000       // N
#define OFF_XPKEY  990000       // C1*32 (u32)
#define OFF_POSSUM 1470000      // C1*3
#define OFF_CNTC1  1515000      // C1
#define OFF_BPMAX  1530000      // C1 (i32)
#define OFF_SUM2   1545000      // C1*64
#define OFF_CNT2   2505000      // C1
#define OFF_X3KEY  2520000      // C2*64 (u32)
#define OFF_B2MAX  3000000      // C2 (i32)
#define OFF_GSUM   3007500      // B*64
#define OFF_GCNT   3008524      // B
#define OFF_MAXABS 3008540      // 1 (u32), padded to 3008544
#define ZERO_ELEMS 3008544
#define OFF_X1     3008544      // N*32
#define OFF_XP     3968544      // C1*32
#define OFF_POSP   4448544      // C1*3
#define OFF_CART   4493544      // E2*3
#define OFF_H2     4793544      // E2*25
#define OFF_T2     7293544      // C1*1664 bf16 (ushort) = 12,480,000 float slots
#define OFF_X2     19773544     // C1*64
// total ~ 20.7M elems = ~83 MB

typedef __attribute__((ext_vector_type(8))) short short8;
typedef __attribute__((ext_vector_type(4))) float f32x4;

__device__ __forceinline__ unsigned fkey(float f) {
    unsigned u = __float_as_uint(f);
    return (u >> 31) ? ~u : (u | 0x80000000u);
}
__device__ __forceinline__ float funkey(unsigned k) {
    unsigned u = (k >> 31) ? (k ^ 0x80000000u) : ~k;
    return __uint_as_float(u);
}
__device__ __forceinline__ float elu(float a) { return a > 0.f ? a : expm1f(a); }

__device__ __forceinline__ unsigned short f2bf(float f) {
    unsigned u = __float_as_uint(f);
    unsigned lsb = (u >> 16) & 1u;
    u += 0x7fffu + lsb;  // round to nearest even
    return (unsigned short)(u >> 16);
}
__device__ __forceinline__ float bf2f(unsigned short s) {
    return __uint_as_float(((unsigned)s) << 16);
}

// ==== conv1 as MFMA GEMM with fused edge-MLP and register-built A ====
// msg[e,o] = sum_{k<25,i<6} h1[e,k]*x[src,i]*w1b[k,i,o] + sum_i x[src,i]*b1b[i,o]
// K-dim permuted (identically on A and B): hw slot u=s*8+j -> (t=u/6, i=u%6),
// logical k = quad + 4*t. k==25 is the bias row (h==1), k>25 and t==7 are zero.
// K padded to 192 -> 6 ksteps, 2 n-halves -> 12 MFMAs per 16-edge tile.
__global__ __launch_bounds__(256, 4) void conv1_mfma(
    const float* __restrict__ x, const float* __restrict__ ea,
    const int* __restrict__ ei,
    const float* __restrict__ w1a, const float* __restrict__ b1a,
    const float* __restrict__ w1b, const float* __restrict__ b1b,
    float* __restrict__ sum1, float* __restrict__ cnt1) {
    const int lane = threadIdx.x & 63;
    const int m = lane & 15;      // A row / B col / C col
    const int q = lane >> 4;      // quad

    // ---- B fragments: load once, keep in registers (6 ksteps x 2 halves) ----
    short8 Bf[6][2];
#pragma unroll
    for (int s = 0; s < 6; ++s) {
#pragma unroll
        for (int h = 0; h < 2; ++h) {
            short8 pk;
#pragma unroll
            for (int j = 0; j < 8; ++j) {
                const int u = s * 8 + j;
                const int t = u / 6, i = u % 6;   // compile-time
                float w = 0.f;
                if (t < 7) {
                    int k = q + 4 * t;            // runtime (quad)
                    int col = h * 16 + m;
                    if (k < 25)       w = w1b[k * 192 + i * 32 + col];
                    else if (k == 25) w = b1b[i * 32 + col];
                }
                pk[j] = (short)f2bf(w);
            }
            Bf[s][h] = pk;
        }
    }

    const int wid = (blockIdx.x * blockDim.x + threadIdx.x) >> 6;
    const int nw = (gridDim.x * blockDim.x) >> 6;
    for (int tile = wid; tile < Ee / 16; tile += nw) {
        const int e0 = tile * 16;
        const int e = e0 + m;
        const int src = ei[e];
        const float ea0 = ea[e * 3], ea1 = ea[e * 3 + 1], ea2 = ea[e * 3 + 2];
        float xs[6];
#pragma unroll
        for (int i = 0; i < 6; ++i) xs[i] = x[src * 6 + i];

        // h values for this lane's logical k = q + 4t
        float hh[8];
#pragma unroll
        for (int t = 0; t < 6; ++t) {  // k = q+4t <= 23, always valid
            int k = q + 4 * t;
            float a = b1a[k] + ea0 * w1a[k] + ea1 * w1a[25 + k] + ea2 * w1a[50 + k];
            hh[t] = fmaxf(a, 0.f);
        }
        {   // t = 6: k = q+24 -> q==0: real k=24; q==1: bias row (h=1); else 0
            if (q == 0) {
                float a = b1a[24] + ea0 * w1a[24] + ea1 * w1a[49] + ea2 * w1a[74];
                hh[6] = fmaxf(a, 0.f);
            } else hh[6] = (q == 1) ? 1.f : 0.f;
        }
        hh[7] = 0.f;

        f32x4 acc0 = {0.f, 0.f, 0.f, 0.f}, acc1 = {0.f, 0.f, 0.f, 0.f};
#pragma unroll
        for (int s = 0; s < 6; ++s) {
            short8 av;
#pragma unroll
            for (int j = 0; j < 8; ++j) {
                const int u = s * 8 + j;
                av[j] = (short)f2bf(hh[u / 6] * xs[u % 6]);  // compile-time reg idx
            }
            acc0 = __builtin_amdgcn_mfma_f32_16x16x32_bf16(av, Bf[s][0], acc0, 0, 0, 0);
            acc1 = __builtin_amdgcn_mfma_f32_16x16x32_bf16(av, Bf[s][1], acc1, 0, 0, 0);
        }

        // C layout: col = lane&15 (=m), row = q*4 + r
#pragma unroll
        for (int r = 0; r < 4; ++r) {
            const int row = q * 4 + r;
            const int dstr = ei[Ee + e0 + row];
            atomicAdd(&sum1[dstr * 32 + m], acc0[r]);
            atomicAdd(&sum1[dstr * 32 + 16 + m], acc1[r]);
        }
        if (q == 0) {
            const int dstm = ei[Ee + e0 + m];
            atomicAdd(&cnt1[dstm], 1.f);
        }
    }
}

__global__ void x1_kernel(const float* __restrict__ sum1, const float* __restrict__ cnt1,
                          const float* __restrict__ x, const float* __restrict__ root1,
                          const float* __restrict__ bias1, float* __restrict__ x1) {
    int t = blockIdx.x * 256 + threadIdx.x;
    if (t >= Nn * 32) return;
    int n = t >> 5, o = t & 31;
    float a = sum1[t] / fmaxf(cnt1[n], 1.f) + bias1[o];
#pragma unroll
    for (int i = 0; i < 6; ++i) a += x[n * 6 + i] * root1[i * 32 + o];
    x1[t] = elu(a);
}

__global__ void pool1_kernel(const float* __restrict__ x1, const float* __restrict__ pos,
                             const int* __restrict__ batch, const int* __restrict__ cluster1,
                             unsigned* __restrict__ xpkey, float* __restrict__ possum,
                             float* __restrict__ cntc1, int* __restrict__ bpmax) {
    int t = blockIdx.x * 256 + threadIdx.x;
    if (t >= Nn * 32) return;
    int n = t >> 5, o = t & 31;
    int c = cluster1[n];
    atomicMax(&xpkey[c * 32 + o], fkey(x1[t]));
    if (o == 0) {
#pragma unroll
        for (int j = 0; j < 3; ++j) atomicAdd(&possum[c * 3 + j], pos[n * 3 + j]);
        atomicAdd(&cntc1[c], 1.f);
        atomicMax(&bpmax[c], batch[n]);
    }
}

__global__ void pool1_final(const unsigned* __restrict__ xpkey, const float* __restrict__ possum,
                            const float* __restrict__ cntc1, float* __restrict__ xp,
                            float* __restrict__ posp) {
    int t = blockIdx.x * 256 + threadIdx.x;
    if (t >= C1n * 32) return;
    int c = t >> 5, o = t & 31;
    unsigned k = xpkey[t];
    xp[t] = k ? funkey(k) : 0.f;
    if (o < 3) posp[c * 3 + o] = possum[c * 3 + o] / fmaxf(cntc1[c], 1.f);
}

__global__ void cart_kernel(const float* __restrict__ posp, const int* __restrict__ ei2,
                            float* __restrict__ cart, unsigned* __restrict__ maxabs) {
    int e = blockIdx.x * 256 + threadIdx.x;
    float mx = 0.f;
    if (e < E2n) {
        int s = ei2[e], d = ei2[E2n + e];
#pragma unroll
        for (int j = 0; j < 3; ++j) {
            float cv = posp[s * 3 + j] - posp[d * 3 + j];
            cart[e * 3 + j] = cv;
            mx = fmaxf(mx, fabsf(cv));
        }
    }
#pragma unroll
    for (int off = 32; off > 0; off >>= 1) mx = fmaxf(mx, __shfl_xor(mx, off));
    if ((threadIdx.x & 63) == 0) atomicMax(maxabs, __float_as_uint(mx));
}

__global__ void h2_kernel(const float* __restrict__ cart, const unsigned* __restrict__ maxabs,
                          const float* __restrict__ w2a, const float* __restrict__ b2a,
                          float* __restrict__ h2) {
    int t = blockIdx.x * 256 + threadIdx.x;
    if (t >= E2n * 25) return;
    int e = t / 25, k = t % 25;
    float inv = 0.5f / __uint_as_float(maxabs[0]);  // 1/(2*max)
    float a = b2a[k];
#pragma unroll
    for (int j = 0; j < 3; ++j) a += (cart[e * 3 + j] * inv + 0.5f) * w2a[j * 25 + k];
    h2[t] = fmaxf(a, 0.f);
}

// ---- T2[n, k, o] = sum_i xp[n,i] * w2baug[k,i,o]; k=25 row = bias; bf16 out ----
__global__ __launch_bounds__(256) void t2_gemm(const float* __restrict__ xp,
                                               const float* __restrict__ w2b,
                                               const float* __restrict__ b2b,
                                               unsigned short* __restrict__ T2) {
    __shared__ float As[256 * 36];
    __shared__ float Bs[32][68];
    const int bm = blockIdx.x * 256;
    const int bn = blockIdx.y * 64;
    const int t = threadIdx.x;
#pragma unroll
    for (int r = 0; r < 8; ++r) {
        int qd = t + r * 256;
        int row = qd >> 3, i4 = (qd & 7) * 4;
        int n = bm + row;
        float4 v = make_float4(0.f, 0.f, 0.f, 0.f);
        if (n < C1n) v = *reinterpret_cast<const float4*>(&xp[n * 32 + i4]);
        *reinterpret_cast<float4*>(&As[row * 36 + i4]) = v;
    }
#pragma unroll
    for (int r = 0; r < 8; ++r) {
        int idx = t + r * 256;
        int i = idx >> 6, nn = idx & 63;
        int col = bn + nn;
        float v;
        if (col < 1600) { int k = col >> 6, o = col & 63; v = w2b[k * 2048 + i * 64 + o]; }
        else            { v = b2b[i * 64 + (col & 63)]; }
        Bs[i][nn] = v;
    }
    __syncthreads();
    const int tn4 = (t & 15) * 4;
    const int tr = t >> 4;
    for (int it = 0; it < 8; ++it) {
        int r0 = it * 32 + tr, r1 = r0 + 16;
        float a0[32], a1[32];
#pragma unroll
        for (int qd = 0; qd < 8; ++qd) {
            *reinterpret_cast<float4*>(&a0[qd * 4]) = *reinterpret_cast<const float4*>(&As[r0 * 36 + qd * 4]);
            *reinterpret_cast<float4*>(&a1[qd * 4]) = *reinterpret_cast<const float4*>(&As[r1 * 36 + qd * 4]);
        }
        float acc0[4] = {0.f, 0.f, 0.f, 0.f}, acc1[4] = {0.f, 0.f, 0.f, 0.f};
#pragma unroll
        for (int k = 0; k < 32; ++k) {
            float4 bv = *reinterpret_cast<const float4*>(&Bs[k][tn4]);
            acc0[0] += a0[k] * bv.x; acc0[1] += a0[k] * bv.y;
            acc0[2] += a0[k] * bv.z; acc0[3] += a0[k] * bv.w;
            acc1[0] += a1[k] * bv.x; acc1[1] += a1[k] * bv.y;
            acc1[2] += a1[k] * bv.z; acc1[3] += a1[k] * bv.w;
        }
        int row0 = bm + r0, row1 = bm + r1;
        if (row0 < C1n) {
            union { unsigned short us[4]; uint2 v; } pk;
            pk.us[0] = f2bf(acc0[0]); pk.us[1] = f2bf(acc0[1]);
            pk.us[2] = f2bf(acc0[2]); pk.us[3] = f2bf(acc0[3]);
            *reinterpret_cast<uint2*>(&T2[(size_t)row0 * 1664 + bn + tn4]) = pk.v;
        }
        if (row1 < C1n) {
            union { unsigned short us[4]; uint2 v; } pk;
            pk.us[0] = f2bf(acc1[0]); pk.us[1] = f2bf(acc1[1]);
            pk.us[2] = f2bf(acc1[2]); pk.us[3] = f2bf(acc1[3]);
            *reinterpret_cast<uint2*>(&T2[(size_t)row1 * 1664 + bn + tn4]) = pk.v;
        }
    }
}

__global__ void conv2_msg(const unsigned short* __restrict__ T2, const float* __restrict__ h2,
                          const int* __restrict__ ei2, float* __restrict__ sum2,
                          float* __restrict__ cnt2) {
    int t = blockIdx.x * 256 + threadIdx.x;
    if (t >= E2n * 64) return;
    int e = t >> 6, o = t & 63;
    int src = ei2[e], dst = ei2[E2n + e];
    const unsigned short* Trow = T2 + (size_t)src * 1664;
    float acc = bf2f(Trow[25 * 64 + o]);  // bias row
#pragma unroll
    for (int k = 0; k < 25; ++k) acc += h2[e * 25 + k] * bf2f(Trow[k * 64 + o]);
    atomicAdd(&sum2[dst * 64 + o], acc);
    if (o == 0) atomicAdd(&cnt2[dst], 1.f);
}

__global__ void x2_kernel(const float* __restrict__ sum2, const float* __restrict__ cnt2,
                          const float* __restrict__ xp, const float* __restrict__ root2,
                          const float* __restrict__ bias2, float* __restrict__ x2) {
    int t = blockIdx.x * 256 + threadIdx.x;
    if (t >= C1n * 64) return;
    int c = t >> 6, o = t & 63;
    float a = sum2[t] / fmaxf(cnt2[c], 1.f) + bias2[o];
#pragma unroll
    for (int i = 0; i < 32; ++i) a += xp[c * 32 + i] * root2[i * 64 + o];
    x2[t] = elu(a);
}

__global__ void pool2_kernel(const float* __restrict__ x2, const int* __restrict__ cluster2,
                             const int* __restrict__ bpmax, unsigned* __restrict__ x3key,
                             int* __restrict__ b2max) {
    int t = blockIdx.x * 256 + threadIdx.x;
    if (t >= C1n * 64) return;
    int c = t >> 6, o = t & 63;
    int c2 = cluster2[c];
    atomicMax(&x3key[c2 * 64 + o], fkey(x2[t]));
    if (o == 0) atomicMax(&b2max[c2], bpmax[c]);
}

__global__ void gacc_kernel(const unsigned* __restrict__ x3key, const int* __restrict__ b2max,
                            float* __restrict__ gsum, float* __restrict__ gcnt) {
    int t = blockIdx.x * 256 + threadIdx.x;
    if (t >= C2n * 64) return;
    int c = t >> 6, o = t & 63;
    int b = b2max[c];
    unsigned k = x3key[t];
    float v = k ? funkey(k) : 0.f;
    atomicAdd(&gsum[b * 64 + o], v);
    if (o == 0) atomicAdd(&gcnt[b], 1.f);
}

__global__ void head_kernel(const float* __restrict__ gsum, const float* __restrict__ gcnt,
                            const float* __restrict__ fc1w, const float* __restrict__ fc1b,
                            const float* __restrict__ fc2w, const float* __restrict__ fc2b,
                            float* __restrict__ out) {
    __shared__ float g[16 * 64];
    __shared__ float hb[16 * 128];
    __shared__ float lg[16 * 10];
    __shared__ float rowm[16];
    int t = threadIdx.x;
    for (int idx = t; idx < 16 * 64; idx += 256) {
        int b = idx >> 6;
        g[idx] = gsum[idx] / fmaxf(gcnt[b], 1.f);
    }
    __syncthreads();
    for (int idx = t; idx < 16 * 128; idx += 256) {
        int b = idx >> 7, j = idx & 127;
        float a = fc1b[j];
        for (int i = 0; i < 64; ++i) a += g[b * 64 + i] * fc1w[i * 128 + j];
        hb[idx] = elu(a);
    }
    __syncthreads();
    for (int idx = t; idx < 160; idx += 256) {
        int b = idx / 10, c = idx % 10;
        float a = fc2b[c];
        for (int i = 0; i < 128; ++i) a += hb[b * 128 + i] * fc2w[i * 10 + c];
        lg[idx] = a;
    }
    __syncthreads();
    if (t < 16) {
        float m = -1e30f;
        for (int c = 0; c < 10; ++c) m = fmaxf(m, lg[t * 10 + c]);
        float s = 0.f;
        for (int c = 0; c < 10; ++c) s += expf(lg[t * 10 + c] - m);
        rowm[t] = m + logf(s);
    }
    __syncthreads();
    for (int idx = t; idx < 160; idx += 256) out[idx] = lg[idx] - rowm[idx / 10];
}

extern "C" void kernel_launch(void* const* d_in, const int* in_sizes, int n_in,
                              void* d_out, int out_size, void* d_ws, size_t ws_size,
                              hipStream_t stream) {
    const float* x     = (const float*)d_in[0];
    const float* ea    = (const float*)d_in[1];
    const float* pos   = (const float*)d_in[2];
    const int*   ei    = (const int*)d_in[3];
    const int*   batch = (const int*)d_in[4];
    const int*   cl1   = (const int*)d_in[5];
    const int*   ei2   = (const int*)d_in[6];
    const int*   cl2   = (const int*)d_in[7];
    const float* w1a   = (const float*)d_in[8];
    const float* b1a   = (const float*)d_in[9];
    const float* w1b   = (const float*)d_in[10];
    const float* b1b   = (const float*)d_in[11];
    const float* root1 = (const float*)d_in[12];
    const float* bias1 = (const float*)d_in[13];
    const float* w2a   = (const float*)d_in[14];
    const float* b2a   = (const float*)d_in[15];
    const float* w2b   = (const float*)d_in[16];
    const float* b2b   = (const float*)d_in[17];
    const float* root2 = (const float*)d_in[18];
    const float* bias2 = (const float*)d_in[19];
    const float* fc1w  = (const float*)d_in[20];
    const float* fc1b  = (const float*)d_in[21];
    const float* fc2w  = (const float*)d_in[22];
    const float* fc2b  = (const float*)d_in[23];
    float* out = (float*)d_out;

    float* ws = (float*)d_ws;
    float*    sum1   = ws + OFF_SUM1;
    float*    cnt1   = ws + OFF_CNT1;
    unsigned* xpkey  = (unsigned*)(ws + OFF_XPKEY);
    float*    possum = ws + OFF_POSSUM;
    float*    cntc1  = ws + OFF_CNTC1;
    int*      bpmax  = (int*)(ws + OFF_BPMAX);
    float*    sum2   = ws + OFF_SUM2;
    float*    cnt2   = ws + OFF_CNT2;
    unsigned* x3key  = (unsigned*)(ws + OFF_X3KEY);
    int*      b2max  = (int*)(ws + OFF_B2MAX);
    float*    gsum   = ws + OFF_GSUM;
    float*    gcnt   = ws + OFF_GCNT;
    unsigned* maxabs = (unsigned*)(ws + OFF_MAXABS);
    float*    x1     = ws + OFF_X1;
    float*    xp     = ws + OFF_XP;
    float*    posp   = ws + OFF_POSP;
    float*    cart   = ws + OFF_CART;
    float*    h2     = ws + OFF_H2;
    unsigned short* T2 = (unsigned short*)(ws + OFF_T2);
    float*    x2     = ws + OFF_X2;

    hipMemsetAsync(ws, 0, (size_t)ZERO_ELEMS * 4, stream);

    conv1_mfma<<<1024, 256, 0, stream>>>(x, ea, ei, w1a, b1a, w1b, b1b, sum1, cnt1);
    x1_kernel<<<(Nn * 32 + 255) / 256, 256, 0, stream>>>(sum1, cnt1, x, root1, bias1, x1);
    pool1_kernel<<<(Nn * 32 + 255) / 256, 256, 0, stream>>>(x1, pos, batch, cl1, xpkey, possum, cntc1, bpmax);
    pool1_final<<<(C1n * 32 + 255) / 256, 256, 0, stream>>>(xpkey, possum, cntc1, xp, posp);
    cart_kernel<<<(E2n + 255) / 256, 256, 0, stream>>>(posp, ei2, cart, maxabs);
    h2_kernel<<<(E2n * 25 + 255) / 256, 256, 0, stream>>>(cart, maxabs, w2a, b2a, h2);
    dim3 tgrid((C1n + 255) / 256, 26);
    t2_gemm<<<tgrid, 256, 0, stream>>>(xp, w2b, b2b, T2);
    conv2_msg<<<(E2n * 64 + 255) / 256, 256, 0, stream>>>(T2, h2, ei2, sum2, cnt2);
    x2_kernel<<<(C1n * 64 + 255) / 256, 256, 0, stream>>>(sum2, cnt2, xp, root2, bias2, x2);
    pool2_kernel<<<(C1n * 64 + 255) / 256, 256, 0, stream>>>(x2, cl2, bpmax, x3key, b2max);
    gacc_kernel<<<(C2n * 64 + 255) / 256, 256, 0, stream>>>(x3key, b2max, gsum, gcnt);
    head_kernel<<<1, 256, 0, stream>>>(gsum, gcnt, fc1w, fc1b, fc2w, fc2b, out);
}

// Round 4
// 352.573 us; speedup vs baseline: 1.7129x; 1.1587x over previous
//
#include <hip/hip_runtime.h>
#include <hip/hip_bf16.h>

#define Nn 30000
#define Ee 400000
#define C1n 15000
#define E2n 100000
#define C2n 7500
#define Bb 16

// ---- workspace layout (float/u32 elements) ----
#define OFF_SUM1   0            // N*32
#define OFF_CNT1   960000       // N
#define OFF_XPKEY  990000       // C1*32 (u32)
#define OFF_POSSUM 1470000      // C1*3
#define OFF_CNTC1  1515000      // C1
#define OFF_BPMAX  1530000      // C1 (i32)
#define OFF_SUM2   1545000      // C1*64
#define OFF_CNT2   2505000      // C1
#define OFF_X3KEY  2520000      // C2*64 (u32)
#define OFF_B2MAX  3000000      // C2 (i32)
#define OFF_GSUM   3007500      // B*64
#define OFF_GCNT   3008524      // B
#define OFF_MAXABS 3008540      // 1 (u32), padded to 3008544
#define ZERO_ELEMS 3008544
#define OFF_X1     3008544      // N*32
#define OFF_XP     3968544      // C1*32
#define OFF_POSP   4448544      // C1*3
#define OFF_CART   4493544      // E2*3
#define OFF_H2     4793544      // E2*25
#define OFF_T2     7293544      // C1*1664 bf16 (ushort) = 12,480,000 float slots
#define OFF_X2     19773544     // C1*64
// total ~ 20.7M elems = ~83 MB

typedef __attribute__((ext_vector_type(8))) short short8;
typedef __attribute__((ext_vector_type(4))) float f32x4;

__device__ __forceinline__ unsigned fkey(float f) {
    unsigned u = __float_as_uint(f);
    return (u >> 31) ? ~u : (u | 0x80000000u);
}
__device__ __forceinline__ float funkey(unsigned k) {
    unsigned u = (k >> 31) ? (k ^ 0x80000000u) : ~k;
    return __uint_as_float(u);
}
__device__ __forceinline__ float elu(float a) { return a > 0.f ? a : expm1f(a); }

__device__ __forceinline__ unsigned short f2bf(float f) {
    unsigned u = __float_as_uint(f);
    unsigned lsb = (u >> 16) & 1u;
    u += 0x7fffu + lsb;  // round to nearest even
    return (unsigned short)(u >> 16);
}
__device__ __forceinline__ float bf2f(unsigned short s) {
    return __uint_as_float(((unsigned)s) << 16);
}

// ==== conv1 as MFMA GEMM with fused edge-MLP and register-built A ====
__global__ __launch_bounds__(256, 4) void conv1_mfma(
    const float* __restrict__ x, const float* __restrict__ ea,
    const int* __restrict__ ei,
    const float* __restrict__ w1a, const float* __restrict__ b1a,
    const float* __restrict__ w1b, const float* __restrict__ b1b,
    float* __restrict__ sum1, float* __restrict__ cnt1) {
    const int lane = threadIdx.x & 63;
    const int m = lane & 15;
    const int q = lane >> 4;

    short8 Bf[6][2];
#pragma unroll
    for (int s = 0; s < 6; ++s) {
#pragma unroll
        for (int h = 0; h < 2; ++h) {
            short8 pk;
#pragma unroll
            for (int j = 0; j < 8; ++j) {
                const int u = s * 8 + j;
                const int t = u / 6, i = u % 6;
                float w = 0.f;
                if (t < 7) {
                    int k = q + 4 * t;
                    int col = h * 16 + m;
                    if (k < 25)       w = w1b[k * 192 + i * 32 + col];
                    else if (k == 25) w = b1b[i * 32 + col];
                }
                pk[j] = (short)f2bf(w);
            }
            Bf[s][h] = pk;
        }
    }

    const int wid = (blockIdx.x * blockDim.x + threadIdx.x) >> 6;
    const int nw = (gridDim.x * blockDim.x) >> 6;
    for (int tile = wid; tile < Ee / 16; tile += nw) {
        const int e0 = tile * 16;
        const int e = e0 + m;
        const int src = ei[e];
        const float ea0 = ea[e * 3], ea1 = ea[e * 3 + 1], ea2 = ea[e * 3 + 2];
        float xs[6];
#pragma unroll
        for (int i = 0; i < 6; ++i) xs[i] = x[src * 6 + i];

        float hh[8];
#pragma unroll
        for (int t = 0; t < 6; ++t) {
            int k = q + 4 * t;
            float a = b1a[k] + ea0 * w1a[k] + ea1 * w1a[25 + k] + ea2 * w1a[50 + k];
            hh[t] = fmaxf(a, 0.f);
        }
        {
            if (q == 0) {
                float a = b1a[24] + ea0 * w1a[24] + ea1 * w1a[49] + ea2 * w1a[74];
                hh[6] = fmaxf(a, 0.f);
            } else hh[6] = (q == 1) ? 1.f : 0.f;
        }
        hh[7] = 0.f;

        f32x4 acc0 = {0.f, 0.f, 0.f, 0.f}, acc1 = {0.f, 0.f, 0.f, 0.f};
#pragma unroll
        for (int s = 0; s < 6; ++s) {
            short8 av;
#pragma unroll
            for (int j = 0; j < 8; ++j) {
                const int u = s * 8 + j;
                av[j] = (short)f2bf(hh[u / 6] * xs[u % 6]);
            }
            acc0 = __builtin_amdgcn_mfma_f32_16x16x32_bf16(av, Bf[s][0], acc0, 0, 0, 0);
            acc1 = __builtin_amdgcn_mfma_f32_16x16x32_bf16(av, Bf[s][1], acc1, 0, 0, 0);
        }

#pragma unroll
        for (int r = 0; r < 4; ++r) {
            const int row = q * 4 + r;
            const int dstr = ei[Ee + e0 + row];
            atomicAdd(&sum1[dstr * 32 + m], acc0[r]);
            atomicAdd(&sum1[dstr * 32 + 16 + m], acc1[r]);
        }
        if (q == 0) {
            const int dstm = ei[Ee + e0 + m];
            atomicAdd(&cnt1[dstm], 1.f);
        }
    }
}

__global__ void x1_kernel(const float* __restrict__ sum1, const float* __restrict__ cnt1,
                          const float* __restrict__ x, const float* __restrict__ root1,
                          const float* __restrict__ bias1, float* __restrict__ x1) {
    int t = blockIdx.x * 256 + threadIdx.x;
    if (t >= Nn * 32) return;
    int n = t >> 5, o = t & 31;
    float a = sum1[t] / fmaxf(cnt1[n], 1.f) + bias1[o];
#pragma unroll
    for (int i = 0; i < 6; ++i) a += x[n * 6 + i] * root1[i * 32 + o];
    x1[t] = elu(a);
}

__global__ void pool1_kernel(const float* __restrict__ x1, const float* __restrict__ pos,
                             const int* __restrict__ batch, const int* __restrict__ cluster1,
                             unsigned* __restrict__ xpkey, float* __restrict__ possum,
                             float* __restrict__ cntc1, int* __restrict__ bpmax) {
    int t = blockIdx.x * 256 + threadIdx.x;
    if (t >= Nn * 32) return;
    int n = t >> 5, o = t & 31;
    int c = cluster1[n];
    atomicMax(&xpkey[c * 32 + o], fkey(x1[t]));
    if (o == 0) {
#pragma unroll
        for (int j = 0; j < 3; ++j) atomicAdd(&possum[c * 3 + j], pos[n * 3 + j]);
        atomicAdd(&cntc1[c], 1.f);
        atomicMax(&bpmax[c], batch[n]);
    }
}

__global__ void pool1_final(const unsigned* __restrict__ xpkey, const float* __restrict__ possum,
                            const float* __restrict__ cntc1, float* __restrict__ xp,
                            float* __restrict__ posp) {
    int t = blockIdx.x * 256 + threadIdx.x;
    if (t >= C1n * 32) return;
    int c = t >> 5, o = t & 31;
    unsigned k = xpkey[t];
    xp[t] = k ? funkey(k) : 0.f;
    if (o < 3) posp[c * 3 + o] = possum[c * 3 + o] / fmaxf(cntc1[c], 1.f);
}

__global__ void cart_kernel(const float* __restrict__ posp, const int* __restrict__ ei2,
                            float* __restrict__ cart, unsigned* __restrict__ maxabs) {
    int e = blockIdx.x * 256 + threadIdx.x;
    float mx = 0.f;
    if (e < E2n) {
        int s = ei2[e], d = ei2[E2n + e];
#pragma unroll
        for (int j = 0; j < 3; ++j) {
            float cv = posp[s * 3 + j] - posp[d * 3 + j];
            cart[e * 3 + j] = cv;
            mx = fmaxf(mx, fabsf(cv));
        }
    }
#pragma unroll
    for (int off = 32; off > 0; off >>= 1) mx = fmaxf(mx, __shfl_xor(mx, off));
    if ((threadIdx.x & 63) == 0) atomicMax(maxabs, __float_as_uint(mx));
}

__global__ void h2_kernel(const float* __restrict__ cart, const unsigned* __restrict__ maxabs,
                          const float* __restrict__ w2a, const float* __restrict__ b2a,
                          float* __restrict__ h2) {
    int t = blockIdx.x * 256 + threadIdx.x;
    if (t >= E2n * 25) return;
    int e = t / 25, k = t % 25;
    float inv = 0.5f / __uint_as_float(maxabs[0]);  // 1/(2*max)
    float a = b2a[k];
#pragma unroll
    for (int j = 0; j < 3; ++j) a += (cart[e * 3 + j] * inv + 0.5f) * w2a[j * 25 + k];
    h2[t] = fmaxf(a, 0.f);
}

// ---- T2[n, k, o] = sum_i xp[n,i] * w2baug[k,i,o]; k=25 row = bias; bf16 out ----
__global__ __launch_bounds__(256) void t2_gemm(const float* __restrict__ xp,
                                               const float* __restrict__ w2b,
                                               const float* __restrict__ b2b,
                                               unsigned short* __restrict__ T2) {
    __shared__ float As[256 * 36];
    __shared__ float Bs[32][68];
    const int bm = blockIdx.x * 256;
    const int bn = blockIdx.y * 64;
    const int t = threadIdx.x;
#pragma unroll
    for (int r = 0; r < 8; ++r) {
        int qd = t + r * 256;
        int row = qd >> 3, i4 = (qd & 7) * 4;
        int n = bm + row;
        float4 v = make_float4(0.f, 0.f, 0.f, 0.f);
        if (n < C1n) v = *reinterpret_cast<const float4*>(&xp[n * 32 + i4]);
        *reinterpret_cast<float4*>(&As[row * 36 + i4]) = v;
    }
#pragma unroll
    for (int r = 0; r < 8; ++r) {
        int idx = t + r * 256;
        int i = idx >> 6, nn = idx & 63;
        int col = bn + nn;
        float v;
        if (col < 1600) { int k = col >> 6, o = col & 63; v = w2b[k * 2048 + i * 64 + o]; }
        else            { v = b2b[i * 64 + (col & 63)]; }
        Bs[i][nn] = v;
    }
    __syncthreads();
    const int tn4 = (t & 15) * 4;
    const int tr = t >> 4;
    for (int it = 0; it < 8; ++it) {
        int r0 = it * 32 + tr, r1 = r0 + 16;
        float a0[32], a1[32];
#pragma unroll
        for (int qd = 0; qd < 8; ++qd) {
            *reinterpret_cast<float4*>(&a0[qd * 4]) = *reinterpret_cast<const float4*>(&As[r0 * 36 + qd * 4]);
            *reinterpret_cast<float4*>(&a1[qd * 4]) = *reinterpret_cast<const float4*>(&As[r1 * 36 + qd * 4]);
        }
        float acc0[4] = {0.f, 0.f, 0.f, 0.f}, acc1[4] = {0.f, 0.f, 0.f, 0.f};
#pragma unroll
        for (int k = 0; k < 32; ++k) {
            float4 bv = *reinterpret_cast<const float4*>(&Bs[k][tn4]);
            acc0[0] += a0[k] * bv.x; acc0[1] += a0[k] * bv.y;
            acc0[2] += a0[k] * bv.z; acc0[3] += a0[k] * bv.w;
            acc1[0] += a1[k] * bv.x; acc1[1] += a1[k] * bv.y;
            acc1[2] += a1[k] * bv.z; acc1[3] += a1[k] * bv.w;
        }
        int row0 = bm + r0, row1 = bm + r1;
        if (row0 < C1n) {
            union { unsigned short us[4]; uint2 v; } pk;
            pk.us[0] = f2bf(acc0[0]); pk.us[1] = f2bf(acc0[1]);
            pk.us[2] = f2bf(acc0[2]); pk.us[3] = f2bf(acc0[3]);
            *reinterpret_cast<uint2*>(&T2[(size_t)row0 * 1664 + bn + tn4]) = pk.v;
        }
        if (row1 < C1n) {
            union { unsigned short us[4]; uint2 v; } pk;
            pk.us[0] = f2bf(acc1[0]); pk.us[1] = f2bf(acc1[1]);
            pk.us[2] = f2bf(acc1[2]); pk.us[3] = f2bf(acc1[3]);
            *reinterpret_cast<uint2*>(&T2[(size_t)row1 * 1664 + bn + tn4]) = pk.v;
        }
    }
}

__global__ void conv2_msg(const unsigned short* __restrict__ T2, const float* __restrict__ h2,
                          const int* __restrict__ ei2, float* __restrict__ sum2,
                          float* __restrict__ cnt2) {
    int t = blockIdx.x * 256 + threadIdx.x;
    if (t >= E2n * 64) return;
    int e = t >> 6, o = t & 63;
    int src = ei2[e], dst = ei2[E2n + e];
    const unsigned short* Trow = T2 + (size_t)src * 1664;
    float acc = bf2f(Trow[25 * 64 + o]);  // bias row
#pragma unroll
    for (int k = 0; k < 25; ++k) acc += h2[e * 25 + k] * bf2f(Trow[k * 64 + o]);
    atomicAdd(&sum2[dst * 64 + o], acc);
    if (o == 0) atomicAdd(&cnt2[dst], 1.f);
}

__global__ void x2_kernel(const float* __restrict__ sum2, const float* __restrict__ cnt2,
                          const float* __restrict__ xp, const float* __restrict__ root2,
                          const float* __restrict__ bias2, float* __restrict__ x2) {
    int t = blockIdx.x * 256 + threadIdx.x;
    if (t >= C1n * 64) return;
    int c = t >> 6, o = t & 63;
    float a = sum2[t] / fmaxf(cnt2[c], 1.f) + bias2[o];
#pragma unroll
    for (int i = 0; i < 32; ++i) a += xp[c * 32 + i] * root2[i * 64 + o];
    x2[t] = elu(a);
}

__global__ void pool2_kernel(const float* __restrict__ x2, const int* __restrict__ cluster2,
                             const int* __restrict__ bpmax, unsigned* __restrict__ x3key,
                             int* __restrict__ b2max) {
    int t = blockIdx.x * 256 + threadIdx.x;
    if (t >= C1n * 64) return;
    int c = t >> 6, o = t & 63;
    int c2 = cluster2[c];
    atomicMax(&x3key[c2 * 64 + o], fkey(x2[t]));
    if (o == 0) atomicMax(&b2max[c2], bpmax[c]);
}

// ---- two-stage batch reduction: LDS partials, then 1 global atomic/slot ----
__global__ __launch_bounds__(256) void gacc_kernel(
    const unsigned* __restrict__ x3key, const int* __restrict__ b2max,
    float* __restrict__ gsum, float* __restrict__ gcnt) {
    __shared__ float ls[Bb * 64];
    __shared__ float lc[Bb];
    const int t = threadIdx.x;
    for (int i = t; i < Bb * 64; i += 256) ls[i] = 0.f;
    if (t < Bb) lc[t] = 0.f;
    __syncthreads();
    const int o = t & 63;
    const int cs = t >> 6;  // 0..3: four clusters in flight per block
    for (int c = blockIdx.x * 4 + cs; c < C2n; c += gridDim.x * 4) {
        int b = b2max[c];
        unsigned k = x3key[c * 64 + o];
        float v = k ? funkey(k) : 0.f;
        atomicAdd(&ls[b * 64 + o], v);   // LDS atomic; lanes hit distinct banks
        if (o == 0) atomicAdd(&lc[b], 1.f);
    }
    __syncthreads();
    for (int i = t; i < Bb * 64; i += 256) {
        float v = ls[i];
        if (v != 0.f) atomicAdd(&gsum[i], v);
    }
    if (t < Bb) {
        float v = lc[t];
        if (v != 0.f) atomicAdd(&gcnt[t], v);
    }
}

__global__ void head_kernel(const float* __restrict__ gsum, const float* __restrict__ gcnt,
                            const float* __restrict__ fc1w, const float* __restrict__ fc1b,
                            const float* __restrict__ fc2w, const float* __restrict__ fc2b,
                            float* __restrict__ out) {
    __shared__ float g[16 * 64];
    __shared__ float hb[16 * 128];
    __shared__ float lg[16 * 10];
    __shared__ float rowm[16];
    int t = threadIdx.x;
    for (int idx = t; idx < 16 * 64; idx += 256) {
        int b = idx >> 6;
        g[idx] = gsum[idx] / fmaxf(gcnt[b], 1.f);
    }
    __syncthreads();
    for (int idx = t; idx < 16 * 128; idx += 256) {
        int b = idx >> 7, j = idx & 127;
        float a = fc1b[j];
        for (int i = 0; i < 64; ++i) a += g[b * 64 + i] * fc1w[i * 128 + j];
        hb[idx] = elu(a);
    }
    __syncthreads();
    for (int idx = t; idx < 160; idx += 256) {
        int b = idx / 10, c = idx % 10;
        float a = fc2b[c];
        for (int i = 0; i < 128; ++i) a += hb[b * 128 + i] * fc2w[i * 10 + c];
        lg[idx] = a;
    }
    __syncthreads();
    if (t < 16) {
        float m = -1e30f;
        for (int c = 0; c < 10; ++c) m = fmaxf(m, lg[t * 10 + c]);
        float s = 0.f;
        for (int c = 0; c < 10; ++c) s += expf(lg[t * 10 + c] - m);
        rowm[t] = m + logf(s);
    }
    __syncthreads();
    for (int idx = t; idx < 160; idx += 256) out[idx] = lg[idx] - rowm[idx / 10];
}

extern "C" void kernel_launch(void* const* d_in, const int* in_sizes, int n_in,
                              void* d_out, int out_size, void* d_ws, size_t ws_size,
                              hipStream_t stream) {
    const float* x     = (const float*)d_in[0];
    const float* ea    = (const float*)d_in[1];
    const float* pos   = (const float*)d_in[2];
    const int*   ei    = (const int*)d_in[3];
    const int*   batch = (const int*)d_in[4];
    const int*   cl1   = (const int*)d_in[5];
    const int*   ei2   = (const int*)d_in[6];
    const int*   cl2   = (const int*)d_in[7];
    const float* w1a   = (const float*)d_in[8];
    const float* b1a   = (const float*)d_in[9];
    const float* w1b   = (const float*)d_in[10];
    const float* b1b   = (const float*)d_in[11];
    const float* root1 = (const float*)d_in[12];
    const float* bias1 = (const float*)d_in[13];
    const float* w2a   = (const float*)d_in[14];
    const float* b2a   = (const float*)d_in[15];
    const float* w2b   = (const float*)d_in[16];
    const float* b2b   = (const float*)d_in[17];
    const float* root2 = (const float*)d_in[18];
    const float* bias2 = (const float*)d_in[19];
    const float* fc1w  = (const float*)d_in[20];
    const float* fc1b  = (const float*)d_in[21];
    const float* fc2w  = (const float*)d_in[22];
    const float* fc2b  = (const float*)d_in[23];
    float* out = (float*)d_out;

    float* ws = (float*)d_ws;
    float*    sum1   = ws + OFF_SUM1;
    float*    cnt1   = ws + OFF_CNT1;
    unsigned* xpkey  = (unsigned*)(ws + OFF_XPKEY);
    float*    possum = ws + OFF_POSSUM;
    float*    cntc1  = ws + OFF_CNTC1;
    int*      bpmax  = (int*)(ws + OFF_BPMAX);
    float*    sum2   = ws + OFF_SUM2;
    float*    cnt2   = ws + OFF_CNT2;
    unsigned* x3key  = (unsigned*)(ws + OFF_X3KEY);
    int*      b2max  = (int*)(ws + OFF_B2MAX);
    float*    gsum   = ws + OFF_GSUM;
    float*    gcnt   = ws + OFF_GCNT;
    unsigned* maxabs = (unsigned*)(ws + OFF_MAXABS);
    float*    x1     = ws + OFF_X1;
    float*    xp     = ws + OFF_XP;
    float*    posp   = ws + OFF_POSP;
    float*    cart   = ws + OFF_CART;
    float*    h2     = ws + OFF_H2;
    unsigned short* T2 = (unsigned short*)(ws + OFF_T2);
    float*    x2     = ws + OFF_X2;

    hipMemsetAsync(ws, 0, (size_t)ZERO_ELEMS * 4, stream);

    conv1_mfma<<<1024, 256, 0, stream>>>(x, ea, ei, w1a, b1a, w1b, b1b, sum1, cnt1);
    x1_kernel<<<(Nn * 32 + 255) / 256, 256, 0, stream>>>(sum1, cnt1, x, root1, bias1, x1);
    pool1_kernel<<<(Nn * 32 + 255) / 256, 256, 0, stream>>>(x1, pos, batch, cl1, xpkey, possum, cntc1, bpmax);
    pool1_final<<<(C1n * 32 + 255) / 256, 256, 0, stream>>>(xpkey, possum, cntc1, xp, posp);
    cart_kernel<<<(E2n + 255) / 256, 256, 0, stream>>>(posp, ei2, cart, maxabs);
    h2_kernel<<<(E2n * 25 + 255) / 256, 256, 0, stream>>>(cart, maxabs, w2a, b2a, h2);
    dim3 tgrid((C1n + 255) / 256, 26);
    t2_gemm<<<tgrid, 256, 0, stream>>>(xp, w2b, b2b, T2);
    conv2_msg<<<(E2n * 64 + 255) / 256, 256, 0, stream>>>(T2, h2, ei2, sum2, cnt2);
    x2_kernel<<<(C1n * 64 + 255) / 256, 256, 0, stream>>>(sum2, cnt2, xp, root2, bias2, x2);
    pool2_kernel<<<(C1n * 64 + 255) / 256, 256, 0, stream>>>(x2, cl2, bpmax, x3key, b2max);
    gacc_kernel<<<32, 256, 0, stream>>>(x3key, b2max, gsum, gcnt);
    head_kernel<<<1, 256, 0, stream>>>(gsum, gcnt, fc1w, fc1b, fc2w, fc2b, out);
}